// Round 5
// baseline (112.108 us; speedup 1.0000x reference)
//
#include <hip/hip_runtime.h>

#define KTOT 65536
#define QN 16
#define DN 64
#define BN 8
#define TILE 256

// smem layout (floats) — 9216 floats = 36,864 B -> 4 blocks/CU (zero-tail residency)
#define QS_OFF 0                    // Q scaled: [16][64]                 = 1024 floats
#define R0_OFF 1024                 // K quarter region 0: [256][16]      = 4096
#define R1_OFF 5120                 // K quarter region 1: [256][16]      = 4096
                                    // R1 doubles as A: per-wave [16][64] slices (wave-private)
#define SMEM_FLOATS 9216

// async global->LDS, 16B per lane; LDS dest linear (wave-uniform base + lane*16)
__device__ __forceinline__ void gload_lds16(const float* g, float* l)
{
    __builtin_amdgcn_global_load_lds(
        (const __attribute__((address_space(1))) void*)g,
        (__attribute__((address_space(3))) void*)l, 16, 0, 0);
}

// Stage one K quarter (16KB: 256 rows x 4 float4) into region RX.
// Source is PRE-SWIZZLED so LDS slot (r,p) holds global col (p ^ ((r>>1)&3));
// read side applies the same XOR.
#define STAGE_QUARTER(RX, kb4, qo4)                                          \
    {                                                                        \
        _Pragma("unroll")                                                    \
        for (int j = 0; j < 4; ++j) {                                        \
            const int s_ = j * 256 + tid;                                    \
            const int r_ = s_ >> 2, p_ = s_ & 3;                             \
            const int f_ = (r_ >> 1) & 3;                                    \
            gload_lds16((const float*)((kb4) + r_ * 16 + (qo4) + (p_ ^ f_)), \
                        (float*)(((float4*)&smem[RX]) + s_));                \
        }                                                                    \
    }

// ---------------- Fused: QK^T + softmax(Q) + attn write + PV partials + norm partials ----------------
// waves_per_eu(4,4): LDS already caps us at 4 blocks/CU (16 waves); pinning min=max=4
// stops the backend from targeting 8 waves/EU (<=64 VGPR) and spilling (round-4 regression:
// VGPR 84->64, FETCH +77MB, WRITE +48MB of scratch traffic).
__attribute__((amdgpu_waves_per_eu(4, 4)))
__global__ __launch_bounds__(256) void fused_attn(
    const float* __restrict__ query, const float* __restrict__ key,
    const float* __restrict__ value, float* __restrict__ attn,
    float* __restrict__ normp, float* __restrict__ upart,
    int NCH, int ntiles)
{
    __shared__ float smem[SMEM_FLOATS];
    const int b    = blockIdx.y;
    const int c    = blockIdx.x;
    const int tid  = threadIdx.x;
    const int wv   = tid >> 6;
    const int lane = tid & 63;
    const int chunk = ntiles * TILE;

    // ---- prologue: issue tile0/quarter0 ASAP (async, no regs), then Q -> LDS ----
    {
        const float4* kb4 = reinterpret_cast<const float4*>(
            key + ((size_t)b * KTOT + c * chunk) * DN);
        STAGE_QUARTER(R0_OFF, kb4, 0);
    }
    {
        float4 qv = reinterpret_cast<const float4*>(query + (size_t)b * QN * DN)[tid];
        qv.x *= 0.125f; qv.y *= 0.125f; qv.z *= 0.125f; qv.w *= 0.125f;
        reinterpret_cast<float4*>(&smem[QS_OFF])[tid] = qv;
    }

    float U[QN], nacc[QN];
    #pragma unroll
    for (int q = 0; q < QN; ++q) { U[q] = 0.f; nacc[q] = 0.f; }

    const int fr = (tid >> 1) & 3;          // read-side swizzle for row tid

    for (int t = 0; t < ntiles; ++t) {
        const int krow0 = c * chunk + t * TILE;
        const float4* kb4 = reinterpret_cast<const float4*>(
            key + ((size_t)b * KTOT + krow0) * DN);

        float s[QN];
        #pragma unroll
        for (int q = 0; q < QN; ++q) s[q] = 0.f;

        // ---- 4 pipelined dot quarters; barrier at top of qt drains the in-flight
        //      quarter qt; quarter qt+1 is issued immediately and rides through the dot ----
        #pragma unroll
        for (int qt = 0; qt < 4; ++qt) {
            __syncthreads();                              // quarter qt visible in R[qt&1]
            if (qt < 3) {
                if (qt & 1) { STAGE_QUARTER(R0_OFF, kb4, (qt + 1) * 4); }
                else        { STAGE_QUARTER(R1_OFF, kb4, (qt + 1) * 4); }
            }
            const int RX = (qt & 1) ? R1_OFF : R0_OFF;
            #pragma unroll
            for (int cc = 0; cc < 4; ++cc) {
                const float4 kv = ((const float4*)&smem[RX])[tid * 4 + (cc ^ fr)];
                #pragma unroll
                for (int q = 0; q < QN; ++q) {
                    const float4 qv = *reinterpret_cast<const float4*>(
                        &smem[QS_OFF + q * DN + qt * 16 + cc * 4]);   // uniform broadcast
                    s[q] = fmaf(kv.x, qv.x, s[q]);
                    s[q] = fmaf(kv.y, qv.y, s[q]);
                    s[q] = fmaf(kv.z, qv.z, s[q]);
                    s[q] = fmaf(kv.w, qv.w, s[q]);
                }
            }
        }

        // ---------- NO BARRIER from here to the end of PV: wave-private dataflow ----------

        // ---- softmax over the 16 queries (thread-local, k = krow0+tid) ----
        float m = s[0];
        #pragma unroll
        for (int q = 1; q < QN; ++q) m = fmaxf(m, s[q]);
        float sum = 0.f;
        #pragma unroll
        for (int q = 0; q < QN; ++q) { s[q] = __expf(s[q] - m); sum += s[q]; }
        const float inv = 1.0f / sum;

        // A lives in this wave's private slice of R1 (rows wv*64..+63 == the slice
        // this wave alone read in qt3); layout [16 q][64 k-local]
        const int AW = R1_OFF + wv * (QN * 64);
        {
            float* ab = attn + (size_t)b * QN * KTOT + krow0 + tid;
            #pragma unroll
            for (int q = 0; q < QN; ++q) {
                const float a = s[q] * inv;
                __builtin_nontemporal_store(a, ab + (size_t)q * KTOT);  // write-once stream
                smem[AW + q * 64 + lane] = a;                           // wave-private, no conflict
                nacc[q] += a;
            }
        }

        // next tile's quarter 0 -> R0: all waves are past the qt3 barrier, so all
        // R0 readers (qt2) are done; rides through the whole barrier-free PV phase
        if (t + 1 < ntiles) { STAGE_QUARTER(R0_OFF, kb4 + TILE * 16, 0); }

        // ---- PV: U[q][lane=d] += a[q][k] * v[k][d]; wave owns 64 k-rows ----
        const float* vptr = value + ((size_t)b * KTOT + krow0 + wv * 64) * DN + lane;
        float va[8];
        #pragma unroll
        for (int i = 0; i < 8; ++i) va[i] = vptr[(size_t)i * DN];   // 256B/instr coalesced
        #pragma unroll 1
        for (int kk = 0; kk < 64; kk += 8) {
            float vb[8];
            const int nxt = kk + 8;
            if (nxt < 64) {
                #pragma unroll
                for (int i = 0; i < 8; ++i) vb[i] = vptr[(size_t)(nxt + i) * DN];
            }
            #pragma unroll
            for (int kq = 0; kq < 8; kq += 4) {
                #pragma unroll
                for (int q = 0; q < QN; ++q) {
                    const float4 av = *reinterpret_cast<const float4*>(
                        &smem[AW + q * 64 + kk + kq]);              // uniform broadcast
                    U[q] = fmaf(av.x, va[kq + 0], U[q]);
                    U[q] = fmaf(av.y, va[kq + 1], U[q]);
                    U[q] = fmaf(av.z, va[kq + 2], U[q]);
                    U[q] = fmaf(av.w, va[kq + 3], U[q]);
                }
            }
            #pragma unroll
            for (int i = 0; i < 8; ++i) va[i] = vb[i];
        }
    }

    // ---- block reductions: U across 4 waves (R0 region), nacc (R1 region) ----
    __syncthreads();
    #pragma unroll
    for (int q = 0; q < QN; ++q)
        smem[R0_OFF + (wv * QN + q) * DN + lane] = U[q];
    #pragma unroll
    for (int q = 0; q < QN; ++q) {
        #pragma unroll
        for (int off = 1; off < 64; off <<= 1)
            nacc[q] += __shfl_xor(nacc[q], off, 64);
    }
    if (lane == 0) {
        #pragma unroll
        for (int q = 0; q < QN; ++q) smem[R1_OFF + wv * QN + q] = nacc[q];
    }
    __syncthreads();

    {
        const int q = tid >> 4, d0 = (tid & 15) * 4;
        const float4 r0 = *reinterpret_cast<const float4*>(&smem[R0_OFF + (0 * QN + q) * DN + d0]);
        const float4 r1 = *reinterpret_cast<const float4*>(&smem[R0_OFF + (1 * QN + q) * DN + d0]);
        const float4 r2 = *reinterpret_cast<const float4*>(&smem[R0_OFF + (2 * QN + q) * DN + d0]);
        const float4 r3 = *reinterpret_cast<const float4*>(&smem[R0_OFF + (3 * QN + q) * DN + d0]);
        float4 rs;
        rs.x = r0.x + r1.x + r2.x + r3.x;
        rs.y = r0.y + r1.y + r2.y + r3.y;
        rs.z = r0.z + r1.z + r2.z + r3.z;
        rs.w = r0.w + r1.w + r2.w + r3.w;
        *reinterpret_cast<float4*>(
            &upart[(((size_t)b * NCH + c) * QN + q) * DN + d0]) = rs;
        if (tid < QN)
            normp[((size_t)b * NCH + c) * QN + tid] =
                smem[R1_OFF + tid] + smem[R1_OFF + QN + tid] +
                smem[R1_OFF + 2 * QN + tid] + smem[R1_OFF + 3 * QN + tid];
    }
}

// ---------------- Finalize: out[b][q][d] = sum_c U / (sum_c norm + eps); grid (8,16) ----------------
__global__ __launch_bounds__(256) void k3_fin(
    const float* __restrict__ upart, const float* __restrict__ normp,
    float* __restrict__ out, int NCH)
{
    const int b = blockIdx.x, q = blockIdx.y;
    const int tid = threadIdx.x;
    const int wv = tid >> 6, lane = tid & 63;

    float nv = 0.f;
    for (int c = tid; c < NCH; c += 256)
        nv += normp[((size_t)b * NCH + c) * QN + q];
    #pragma unroll
    for (int off = 1; off < 64; off <<= 1) nv += __shfl_xor(nv, off, 64);
    __shared__ float nred[4];
    if (lane == 0) nred[wv] = nv;

    float acc = 0.f;
    for (int c = wv; c < NCH; c += 4)
        acc += upart[(((size_t)b * NCH + c) * QN + q) * DN + lane];
    __shared__ float ured[4][DN];
    ured[wv][lane] = acc;
    __syncthreads();

    if (tid < DN) {
        const float n   = nred[0] + nred[1] + nred[2] + nred[3];
        const float inv = 1.0f / (n + 1e-8f);
        const float u   = ured[0][tid] + ured[1][tid] + ured[2][tid] + ured[3][tid];
        out[((size_t)b * QN + q) * DN + tid] = u * inv;
    }
}

extern "C" void kernel_launch(void* const* d_in, const int* in_sizes, int n_in,
                              void* d_out, int out_size, void* d_ws, size_t ws_size,
                              hipStream_t stream)
{
    const float* query = (const float*)d_in[0];
    const float* key   = (const float*)d_in[1];
    const float* value = (const float*)d_in[2];

    float* out  = (float*)d_out;                          // [8,16,64]
    float* attn = (float*)d_out + (size_t)BN * QN * DN;   // [8,1,16,65536]

    int NCH = 128;                                        // 1024 blocks = 4/CU resident, zero tail
    while (NCH > 8 && (size_t)BN * NCH * QN * (DN + 1) * 4 > ws_size) NCH >>= 1;
    const int ntiles = (KTOT / NCH) / TILE;

    float* normp = (float*)d_ws;                          // [8][NCH][16]
    float* upart = (float*)d_ws + (size_t)BN * NCH * QN;  // [8][NCH][16][64]

    fused_attn<<<dim3(NCH, BN), 256, 0, stream>>>(query, key, value, attn,
                                                  normp, upart, NCH, ntiles);
    k3_fin   <<<dim3(BN, QN), 256, 0, stream>>>(upart, normp, out, NCH);
}

// Round 6
// 109.758 us; speedup vs baseline: 1.0214x; 1.0214x over previous
//
#include <hip/hip_runtime.h>

#define KTOT 65536
#define QN 16
#define DN 64
#define BN 8
#define TILE 256

// smem layout (floats) — 9216 floats = 36,864 B -> 4 blocks/CU (zero-tail residency)
#define QS_OFF 0                    // Q scaled: [16][64]                 = 1024 floats
#define R0_OFF 1024                 // K quarter region 0: [256][16]      = 4096
#define R1_OFF 5120                 // K quarter region 1: [256][16]      = 4096
                                    // R1 doubles as A: per-wave [16][64] slices (wave-private)
#define SMEM_FLOATS 9216

// async global->LDS, 16B per lane; LDS dest linear (wave-uniform base + lane*16)
__device__ __forceinline__ void gload_lds16(const float* g, float* l)
{
    __builtin_amdgcn_global_load_lds(
        (const __attribute__((address_space(1))) void*)g,
        (__attribute__((address_space(3))) void*)l, 16, 0, 0);
}

// Stage one K quarter (16KB: 256 rows x 4 float4) into region RX.
// Source is PRE-SWIZZLED so LDS slot (r,p) holds global col (p ^ ((r>>1)&3));
// read side applies the same XOR.
#define STAGE_QUARTER(RX, kb4, qo4)                                          \
    {                                                                        \
        _Pragma("unroll")                                                    \
        for (int j = 0; j < 4; ++j) {                                        \
            const int s_ = j * 256 + tid;                                    \
            const int r_ = s_ >> 2, p_ = s_ & 3;                             \
            const int f_ = (r_ >> 1) & 3;                                    \
            gload_lds16((const float*)((kb4) + r_ * 16 + (qo4) + (p_ ^ f_)), \
                        (float*)(((float4*)&smem[RX]) + s_));                \
        }                                                                    \
    }

// ---------------- Fused: QK^T + softmax(Q) + attn write + PV partials + norm partials ----------------
// __launch_bounds__(256, 3): min-waves/EU=3 gives the allocator a ~170-reg budget, so the
// ~84-reg live set fits spill-free (round 3 evidence). Occupancy is LDS-limited to
// 4 blocks/CU (36,864 B each) regardless, and 84 <= 128 so all 4 blocks remain resident.
// Rounds 4/5 showed (256,4) / waves_per_eu(4,4) both squeeze to 64 VGPR -> ~78 MB/dispatch
// of scratch traffic (FETCH 144->221 MB), cancelling the occupancy win.
__global__ __launch_bounds__(256, 3) void fused_attn(
    const float* __restrict__ query, const float* __restrict__ key,
    const float* __restrict__ value, float* __restrict__ attn,
    float* __restrict__ normp, float* __restrict__ upart,
    int NCH, int ntiles)
{
    __shared__ float smem[SMEM_FLOATS];
    const int b    = blockIdx.y;
    const int c    = blockIdx.x;
    const int tid  = threadIdx.x;
    const int wv   = tid >> 6;
    const int lane = tid & 63;
    const int chunk = ntiles * TILE;

    // ---- prologue: issue tile0/quarter0 ASAP (async, no regs), then Q -> LDS ----
    {
        const float4* kb4 = reinterpret_cast<const float4*>(
            key + ((size_t)b * KTOT + c * chunk) * DN);
        STAGE_QUARTER(R0_OFF, kb4, 0);
    }
    {
        float4 qv = reinterpret_cast<const float4*>(query + (size_t)b * QN * DN)[tid];
        qv.x *= 0.125f; qv.y *= 0.125f; qv.z *= 0.125f; qv.w *= 0.125f;
        reinterpret_cast<float4*>(&smem[QS_OFF])[tid] = qv;
    }

    float U[QN], nacc[QN];
    #pragma unroll
    for (int q = 0; q < QN; ++q) { U[q] = 0.f; nacc[q] = 0.f; }

    const int fr = (tid >> 1) & 3;          // read-side swizzle for row tid

    for (int t = 0; t < ntiles; ++t) {
        const int krow0 = c * chunk + t * TILE;
        const float4* kb4 = reinterpret_cast<const float4*>(
            key + ((size_t)b * KTOT + krow0) * DN);

        float s[QN];
        #pragma unroll
        for (int q = 0; q < QN; ++q) s[q] = 0.f;

        // ---- 4 pipelined dot quarters; barrier at top of qt drains the in-flight
        //      quarter qt; quarter qt+1 is issued immediately and rides through the dot ----
        #pragma unroll
        for (int qt = 0; qt < 4; ++qt) {
            __syncthreads();                              // quarter qt visible in R[qt&1]
            if (qt < 3) {
                if (qt & 1) { STAGE_QUARTER(R0_OFF, kb4, (qt + 1) * 4); }
                else        { STAGE_QUARTER(R1_OFF, kb4, (qt + 1) * 4); }
            }
            const int RX = (qt & 1) ? R1_OFF : R0_OFF;
            #pragma unroll
            for (int cc = 0; cc < 4; ++cc) {
                const float4 kv = ((const float4*)&smem[RX])[tid * 4 + (cc ^ fr)];
                #pragma unroll
                for (int q = 0; q < QN; ++q) {
                    const float4 qv = *reinterpret_cast<const float4*>(
                        &smem[QS_OFF + q * DN + qt * 16 + cc * 4]);   // uniform broadcast
                    s[q] = fmaf(kv.x, qv.x, s[q]);
                    s[q] = fmaf(kv.y, qv.y, s[q]);
                    s[q] = fmaf(kv.z, qv.z, s[q]);
                    s[q] = fmaf(kv.w, qv.w, s[q]);
                }
            }
        }

        // ---------- NO BARRIER from here to the end of PV: wave-private dataflow ----------

        // ---- softmax over the 16 queries (thread-local, k = krow0+tid) ----
        float m = s[0];
        #pragma unroll
        for (int q = 1; q < QN; ++q) m = fmaxf(m, s[q]);
        float sum = 0.f;
        #pragma unroll
        for (int q = 0; q < QN; ++q) { s[q] = __expf(s[q] - m); sum += s[q]; }
        const float inv = 1.0f / sum;

        // A lives in this wave's private slice of R1 (rows wv*64..+63 == the slice
        // this wave alone read in qt3); layout [16 q][64 k-local]
        const int AW = R1_OFF + wv * (QN * 64);
        {
            float* ab = attn + (size_t)b * QN * KTOT + krow0 + tid;
            #pragma unroll
            for (int q = 0; q < QN; ++q) {
                const float a = s[q] * inv;
                __builtin_nontemporal_store(a, ab + (size_t)q * KTOT);  // write-once stream
                smem[AW + q * 64 + lane] = a;                           // wave-private, no conflict
                nacc[q] += a;
            }
        }

        // next tile's quarter 0 -> R0: all waves are past the qt3 barrier, so all
        // R0 readers (qt2) are done; rides through the whole barrier-free PV phase
        if (t + 1 < ntiles) { STAGE_QUARTER(R0_OFF, kb4 + TILE * 16, 0); }

        // ---- PV: U[q][lane=d] += a[q][k] * v[k][d]; wave owns 64 k-rows ----
        const float* vptr = value + ((size_t)b * KTOT + krow0 + wv * 64) * DN + lane;
        float va[8];
        #pragma unroll
        for (int i = 0; i < 8; ++i) va[i] = vptr[(size_t)i * DN];   // 256B/instr coalesced
        #pragma unroll 1
        for (int kk = 0; kk < 64; kk += 8) {
            float vb[8];
            const int nxt = kk + 8;
            if (nxt < 64) {
                #pragma unroll
                for (int i = 0; i < 8; ++i) vb[i] = vptr[(size_t)(nxt + i) * DN];
            }
            #pragma unroll
            for (int kq = 0; kq < 8; kq += 4) {
                #pragma unroll
                for (int q = 0; q < QN; ++q) {
                    const float4 av = *reinterpret_cast<const float4*>(
                        &smem[AW + q * 64 + kk + kq]);              // uniform broadcast
                    U[q] = fmaf(av.x, va[kq + 0], U[q]);
                    U[q] = fmaf(av.y, va[kq + 1], U[q]);
                    U[q] = fmaf(av.z, va[kq + 2], U[q]);
                    U[q] = fmaf(av.w, va[kq + 3], U[q]);
                }
            }
            #pragma unroll
            for (int i = 0; i < 8; ++i) va[i] = vb[i];
        }
    }

    // ---- block reductions: U across 4 waves (R0 region), nacc (R1 region) ----
    __syncthreads();
    #pragma unroll
    for (int q = 0; q < QN; ++q)
        smem[R0_OFF + (wv * QN + q) * DN + lane] = U[q];
    #pragma unroll
    for (int q = 0; q < QN; ++q) {
        #pragma unroll
        for (int off = 1; off < 64; off <<= 1)
            nacc[q] += __shfl_xor(nacc[q], off, 64);
    }
    if (lane == 0) {
        #pragma unroll
        for (int q = 0; q < QN; ++q) smem[R1_OFF + wv * QN + q] = nacc[q];
    }
    __syncthreads();

    {
        const int q = tid >> 4, d0 = (tid & 15) * 4;
        const float4 r0 = *reinterpret_cast<const float4*>(&smem[R0_OFF + (0 * QN + q) * DN + d0]);
        const float4 r1 = *reinterpret_cast<const float4*>(&smem[R0_OFF + (1 * QN + q) * DN + d0]);
        const float4 r2 = *reinterpret_cast<const float4*>(&smem[R0_OFF + (2 * QN + q) * DN + d0]);
        const float4 r3 = *reinterpret_cast<const float4*>(&smem[R0_OFF + (3 * QN + q) * DN + d0]);
        float4 rs;
        rs.x = r0.x + r1.x + r2.x + r3.x;
        rs.y = r0.y + r1.y + r2.y + r3.y;
        rs.z = r0.z + r1.z + r2.z + r3.z;
        rs.w = r0.w + r1.w + r2.w + r3.w;
        *reinterpret_cast<float4*>(
            &upart[(((size_t)b * NCH + c) * QN + q) * DN + d0]) = rs;
        if (tid < QN)
            normp[((size_t)b * NCH + c) * QN + tid] =
                smem[R1_OFF + tid] + smem[R1_OFF + QN + tid] +
                smem[R1_OFF + 2 * QN + tid] + smem[R1_OFF + 3 * QN + tid];
    }
}

// ---------------- Finalize: out[b][q][d] = sum_c U / (sum_c norm + eps); grid (8,16) ----------------
__global__ __launch_bounds__(256) void k3_fin(
    const float* __restrict__ upart, const float* __restrict__ normp,
    float* __restrict__ out, int NCH)
{
    const int b = blockIdx.x, q = blockIdx.y;
    const int tid = threadIdx.x;
    const int wv = tid >> 6, lane = tid & 63;

    float nv = 0.f;
    for (int c = tid; c < NCH; c += 256)
        nv += normp[((size_t)b * NCH + c) * QN + q];
    #pragma unroll
    for (int off = 1; off < 64; off <<= 1) nv += __shfl_xor(nv, off, 64);
    __shared__ float nred[4];
    if (lane == 0) nred[wv] = nv;

    float acc = 0.f;
    for (int c = wv; c < NCH; c += 4)
        acc += upart[(((size_t)b * NCH + c) * QN + q) * DN + lane];
    __shared__ float ured[4][DN];
    ured[wv][lane] = acc;
    __syncthreads();

    if (tid < DN) {
        const float n   = nred[0] + nred[1] + nred[2] + nred[3];
        const float inv = 1.0f / (n + 1e-8f);
        const float u   = ured[0][tid] + ured[1][tid] + ured[2][tid] + ured[3][tid];
        out[((size_t)b * QN + q) * DN + tid] = u * inv;
    }
}

extern "C" void kernel_launch(void* const* d_in, const int* in_sizes, int n_in,
                              void* d_out, int out_size, void* d_ws, size_t ws_size,
                              hipStream_t stream)
{
    const float* query = (const float*)d_in[0];
    const float* key   = (const float*)d_in[1];
    const float* value = (const float*)d_in[2];

    float* out  = (float*)d_out;                          // [8,16,64]
    float* attn = (float*)d_out + (size_t)BN * QN * DN;   // [8,1,16,65536]

    int NCH = 128;                                        // 1024 blocks = 4/CU resident, zero tail
    while (NCH > 8 && (size_t)BN * NCH * QN * (DN + 1) * 4 > ws_size) NCH >>= 1;
    const int ntiles = (KTOT / NCH) / TILE;

    float* normp = (float*)d_ws;                          // [8][NCH][16]
    float* upart = (float*)d_ws + (size_t)BN * NCH * QN;  // [8][NCH][16][64]

    fused_attn<<<dim3(NCH, BN), 256, 0, stream>>>(query, key, value, attn,
                                                  normp, upart, NCH, ntiles);
    k3_fin   <<<dim3(BN, QN), 256, 0, stream>>>(upart, normp, out, NCH);
}